// Round 7
// baseline (4182.071 us; speedup 1.0000x reference)
//
#include <hip/hip_runtime.h>
#include <math.h>

#define B_    4096
#define CIN   60
#define CW    32
#define EMB   512
#define TSTEP 50
#define KFC   1152   // 36*32 (pos-major, co-minor layout!)
#define G3    1536

typedef _Float16 f16;
typedef _Float16 f16x4 __attribute__((ext_vector_type(4)));
typedef _Float16 f16x8 __attribute__((ext_vector_type(8)));
typedef float    f32x4 __attribute__((ext_vector_type(4)));
typedef float    f32x16 __attribute__((ext_vector_type(16)));

typedef __attribute__((address_space(3))) void       lds_void_t;
typedef __attribute__((address_space(1))) const void g_void_t;

__device__ __forceinline__ float sigmoid_fast(float x){ return 1.f/(1.f+__expf(-x)); }
__device__ __forceinline__ float tanh_fast(float x){ float e=__expf(2.f*x); return 1.f-2.f/(e+1.f); }

// ---------- fused weight prep ----------
// w_hh -> w16T [64 kc][1536 R][8] f16 (k-major);  conv_w -> w16c swizzled;
// fc_w -> fcp16 permuted;  out init;  bar zero.
__global__ void prep_kernel(const float* __restrict__ w_hh, f16* __restrict__ w16T,
                            const float* __restrict__ conv_w, f16* __restrict__ w16c,
                            const float* __restrict__ fc_w, f16* __restrict__ fcp16,
                            const float* __restrict__ dec_b, float* __restrict__ out,
                            int* __restrict__ bar)
{
    int i = blockIdx.x * 256 + threadIdx.x;
    if (i < G3 * EMB) {
        int R = i >> 9, k = i & 511;
        w16T[(size_t)(k >> 3) * 12288 + R * 8 + (k & 7)] = (f16)w_hh[i];
        return;
    }
    i -= G3 * EMB;
    if (i < 9 * 32 * 64) {
        int khkw = i >> 11, r = i & 2047, co = r >> 6, ci = r & 63;
        float v = (ci < CIN) ? conv_w[(co * CIN + ci) * 9 + khkw] : 0.f;
        int dst = khkw * 2048 + co * 64 + (((ci >> 3) ^ (co & 7)) << 3) + (ci & 7);
        w16c[dst] = (f16)v;
        return;
    }
    i -= 9 * 32 * 64;
    if (i < EMB * KFC) {
        int e = i / KFC, j = i % KFC;
        int co = j & 31, pos = j >> 5;
        fcp16[i] = (f16)fc_w[e * KFC + co * 36 + pos];
        return;
    }
    i -= EMB * KFC;
    if (i < B_ * TSTEP) { out[i] = dec_b[0]; return; }
    i -= B_ * TSTEP;
    if (i < 1024) bar[i] = 0;
}

// ---------- conv 3x3 VALID + relu via im2col MFMA, weights in registers ----------
__global__ __launch_bounds__(256) void conv_mfma(
    const float* __restrict__ x, const f16* __restrict__ w16c,
    const float* __restrict__ conv_b, f16* __restrict__ outc)
{
    __shared__ __align__(16) f16 xt[8 * 64 * 64];    // 64 KB
    int tid = threadIdx.x, wid = tid >> 6, lane = tid & 63;
    int b0 = blockIdx.x * 8;
    int mhalf = wid >> 1, nt = wid & 1;
    int lrow = lane & 15, kgrp = lane >> 4;
    int co = nt * 16 + lrow;

    f16x8 bfr[18];
    #pragma unroll
    for (int ks = 0; ks < 18; ks++) {
        int khkw = ks >> 1, c = (ks & 1) * 4 + kgrp;
        bfr[ks] = *(const f16x8*)((const char*)w16c +
                    khkw * 4096 + co * 128 + ((c ^ (co & 7)) << 4));
    }
    float cb = conv_b[co];

    #pragma unroll
    for (int bt = 0; bt < 3; bt++) {
        float ra[10][4];
        #pragma unroll
        for (int j = 0; j < 10; j++) {
            int idx = (bt * 10 + j) * 4 + wid;
            int img = idx / 15, cq = idx - img * 15;
            const float* xp = x + ((size_t)(b0 + img) * CIN + cq * 4) * 64 + lane;
            ra[j][0] = xp[0]; ra[j][1] = xp[64]; ra[j][2] = xp[128]; ra[j][3] = xp[192];
        }
        #pragma unroll
        for (int j = 0; j < 10; j++) {
            int idx = (bt * 10 + j) * 4 + wid;
            int img = idx / 15, cq = idx - img * 15;
            f16x4 v = { (f16)ra[j][0], (f16)ra[j][1], (f16)ra[j][2], (f16)ra[j][3] };
            int off = img * 8192 + lane * 128 + (((cq >> 1) ^ (lane & 7)) << 4) + (cq & 1) * 8;
            *(f16x4*)((char*)xt + off) = v;
        }
    }
    #pragma unroll
    for (int i = 0; i < 2; i++) {
        int s = i * 256 + tid, img = s >> 6, px = s & 63;
        int off = img * 8192 + px * 128 + ((7 ^ (px & 7)) << 4) + 8;
        *(f16x4*)((char*)xt + off) = f16x4{0, 0, 0, 0};
    }
    __syncthreads();

    int imgs[9], pxb[9];
    #pragma unroll
    for (int i = 0; i < 9; i++) {
        int row = mhalf * 144 + i * 16 + lrow;
        int img = (row * 1821) >> 16, pos = row - img * 36;
        int oh = (pos * 43) >> 8, ow = pos - oh * 6;
        imgs[i] = img; pxb[i] = oh * 8 + ow;
    }

    f32x4 acc[9];
    #pragma unroll
    for (int i = 0; i < 9; i++) acc[i] = f32x4{0, 0, 0, 0};

    #pragma unroll
    for (int ks = 0; ks < 18; ks++) {
        int khkw = ks >> 1;
        int kh = khkw / 3, kw = khkw - kh * 3;
        int c = (ks & 1) * 4 + kgrp;
        #pragma unroll
        for (int i = 0; i < 9; i++) {
            int px = pxb[i] + kh * 8 + kw;
            f16x8 af = *(const f16x8*)((const char*)xt +
                         imgs[i] * 8192 + px * 128 + ((c ^ (px & 7)) << 4));
            acc[i] = __builtin_amdgcn_mfma_f32_16x16x32_f16(af, bfr[ks], acc[i], 0, 0, 0);
        }
    }

    #pragma unroll
    for (int i = 0; i < 9; i++) {
        #pragma unroll
        for (int j = 0; j < 4; j++) {
            int row = mhalf * 144 + i * 16 + kgrp * 4 + j;
            int img = (row * 1821) >> 16, pos = row - img * 36;
            float v = fmaxf(acc[i][j] + cb, 0.f);
            outc[(size_t)(b0 + img) * KFC + pos * 32 + co] = (f16)v;
        }
    }
}

// ---------- FC: f16 MFMA GEMM, relu -> h16T [64 kc][4096 m][8] ----------
__global__ __launch_bounds__(256) void fc_mfma(
    const f16* __restrict__ A, const f16* __restrict__ Bm,
    const float* __restrict__ bias, f16* __restrict__ h16T)
{
    __shared__ __align__(16) f16 As[2][64 * 64];
    __shared__ __align__(16) f16 Bs[2][64 * 64];
    int tid = threadIdx.x, wid = tid >> 6, lane = tid & 63;
    int wr = wid >> 1, wc = wid & 1;
    int col = lane & 31, half = lane >> 5;
    int m0 = blockIdx.y * 64, n0 = blockIdx.x * 64;

    const f16* gA[2]; const f16* gB[2];
    #pragma unroll
    for (int i = 0; i < 2; i++) {
        int q = i * 256 + tid, row = q >> 3, cp = q & 7, c = cp ^ (row & 7);
        gA[i] = A  + (size_t)(m0 + row) * KFC + c * 8;
        gB[i] = Bm + (size_t)(n0 + row) * KFC + c * 8;
    }
    auto stage = [&](int buf, int k0) {
        #pragma unroll
        for (int i = 0; i < 2; i++)
            __builtin_amdgcn_global_load_lds((const g_void_t*)(gA[i] + k0),
                (lds_void_t*)((char*)&As[buf][0] + (i * 256 + wid * 64) * 16), 16, 0, 0);
        #pragma unroll
        for (int i = 0; i < 2; i++)
            __builtin_amdgcn_global_load_lds((const g_void_t*)(gB[i] + k0),
                (lds_void_t*)((char*)&Bs[buf][0] + (i * 256 + wid * 64) * 16), 16, 0, 0);
    };

    f32x16 acc;
    #pragma unroll
    for (int r = 0; r < 16; r++) acc[r] = 0.f;

    stage(0, 0); stage(1, 64);
    int cur = 0, arow = wr * 32 + col, brow = wc * 32 + col;
    #pragma unroll 1
    for (int kt = 0; kt < 17; kt++) {
        asm volatile("s_waitcnt vmcnt(4)" ::: "memory");
        __builtin_amdgcn_s_barrier();
        __builtin_amdgcn_sched_barrier(0);
        __builtin_amdgcn_s_setprio(1);
        #pragma unroll
        for (int kk = 0; kk < 4; kk++) {
            int ch = kk * 2 + half;
            f16x8 af = *(const f16x8*)&As[cur][arow * 64 + ((ch ^ (arow & 7)) << 3)];
            f16x8 bf = *(const f16x8*)&Bs[cur][brow * 64 + ((ch ^ (brow & 7)) << 3)];
            acc = __builtin_amdgcn_mfma_f32_32x32x16_f16(af, bf, acc, 0, 0, 0);
        }
        __builtin_amdgcn_s_setprio(0);
        __builtin_amdgcn_sched_barrier(0);
        __builtin_amdgcn_s_barrier();
        if (kt < 16) stage(cur, (kt + 2) * 64);
        cur ^= 1;
    }
    asm volatile("s_waitcnt vmcnt(0)" ::: "memory");
    __builtin_amdgcn_s_barrier();
    __builtin_amdgcn_sched_barrier(0);
    #pragma unroll
    for (int kk = 0; kk < 4; kk++) {
        int ch = kk * 2 + half;
        f16x8 af = *(const f16x8*)&As[cur][arow * 64 + ((ch ^ (arow & 7)) << 3)];
        f16x8 bf = *(const f16x8*)&Bs[cur][brow * 64 + ((ch ^ (brow & 7)) << 3)];
        acc = __builtin_amdgcn_mfma_f32_32x32x16_f16(af, bf, acc, 0, 0, 0);
    }

    #pragma unroll
    for (int r = 0; r < 16; r++) {
        int m = m0 + wr * 32 + (r & 3) + 8 * (r >> 2) + 4 * half;
        int n = n0 + wc * 32 + col;
        float v = fmaxf(acc[r] + bias[n], 0.f);
        h16T[(size_t)(n >> 3) * 32768 + m * 8 + (n & 7)] = (f16)v;
    }
}

// ---------- persistent GRU: all 50 steps, W LDS-resident, per-m-group barriers ----------
// Regular launch, 256 blocks x 256 thr, 1 block/CU (128 KiB LDS) -> all co-resident.
// Block: 256 m x 32 e x 3 gates, full K=512.
// LDS: Blds [64 kc][96 brow][8] = 96 KB (loaded once) + Alds dbuf 2x16 KB.
// h k-major: h16T[kc][m][8] -> coalesced global_load_lds AND conflict-free ds_read.
__global__ __launch_bounds__(256, 1) void gru_persist(
    f16* __restrict__ h_a, f16* __restrict__ h_b,
    const f16* __restrict__ w16T, const float* __restrict__ b_hh,
    const float* __restrict__ w_ih, const float* __restrict__ b_ih,
    const float* __restrict__ dec_w, float* __restrict__ out,
    int* __restrict__ bar)
{
    __shared__ __align__(16) f16 Blds[64 * 96 * 8];     // 98304 B
    __shared__ __align__(16) f16 Alds[2][4 * 256 * 8];  // 32768 B
    int tid = threadIdx.x, wid = tid >> 6, lane = tid & 63;
    int col = lane & 31, half = lane >> 5;
    int bid = blockIdx.x;
    int xc = bid & 7, y = bid >> 3;
    int mg = xc * 2 + (y >> 4), eg = y & 15;     // 16 blocks of an m-group share an XCD
    int m0 = mg * 256, e0 = eg * 32;
    int e = e0 + col;

    // one-time B load (96 KB), LDS dest wave-linear, global source per-lane
    #pragma unroll
    for (int i = 0; i < 24; i++) {
        int cell = i * 256 + tid;
        int kc = cell / 96, brow = cell - kc * 96;
        int g = brow >> 5, c = brow & 31;
        __builtin_amdgcn_global_load_lds(
            (const g_void_t*)(w16T + (size_t)kc * 12288 + (g * 512 + e0 + c) * 8),
            (lds_void_t*)((char*)Blds + (i * 256 + wid * 64) * 16), 16, 0, 0);
    }
    float wir = w_ih[e], wiz = w_ih[EMB + e], win = w_ih[2 * EMB + e];
    float bir = b_ih[e], biz = b_ih[EMB + e], bin_ = b_ih[2 * EMB + e];
    float bhr = b_hh[e], bhz = b_hh[EMB + e], bhn = b_hh[2 * EMB + e];
    float dw  = dec_w[e];
    asm volatile("s_waitcnt vmcnt(0)" ::: "memory");
    __syncthreads();

    int vbar = mg * 64;
    #pragma unroll 1
    for (int t = 0; t < TSTEP; t++) {
        const f16* hin = (t & 1) ? h_b : h_a;
        f16*       hout = (t & 1) ? h_a : h_b;

        if (t > 0) {
            if (tid == 0) {
                while (__hip_atomic_load(&bar[vbar + t - 1], __ATOMIC_ACQUIRE,
                                         __HIP_MEMORY_SCOPE_AGENT) < 16)
                    __builtin_amdgcn_s_sleep(1);
            }
            __syncthreads();
            __threadfence();               // acquire: fresh view of hin + out[:,t-1]
        }

        auto stage = [&](int buf, int kt4) {
            #pragma unroll
            for (int i = 0; i < 4; i++)
                __builtin_amdgcn_global_load_lds(
                    (const g_void_t*)(hin + (size_t)(kt4 * 4 + i) * 32768 + (m0 + tid) * 8),
                    (lds_void_t*)((char*)&Alds[buf][0] + (i * 256 + wid * 64) * 16), 16, 0, 0);
        };

        f32x16 acc[3][2];
        #pragma unroll
        for (int g = 0; g < 3; g++)
            #pragma unroll
            for (int mi = 0; mi < 2; mi++)
                #pragma unroll
                for (int r = 0; r < 16; r++) acc[g][mi][r] = 0.f;

        stage(0, 0); stage(1, 1);
        int cur = 0;
        #pragma unroll 1
        for (int kt = 0; kt < 16; kt++) {
            if (kt < 15) asm volatile("s_waitcnt vmcnt(4)" ::: "memory");
            else         asm volatile("s_waitcnt vmcnt(0)" ::: "memory");
            __builtin_amdgcn_s_barrier();
            __builtin_amdgcn_sched_barrier(0);
            __builtin_amdgcn_s_setprio(1);
            #pragma unroll
            for (int kk = 0; kk < 2; kk++) {
                int kc = kk * 2 + half;                       // 0..3
                f16x8 af0 = *(const f16x8*)&Alds[cur][(kc * 256 + wid * 64 + col) * 8];
                f16x8 af1 = *(const f16x8*)&Alds[cur][(kc * 256 + wid * 64 + 32 + col) * 8];
                #pragma unroll
                for (int g = 0; g < 3; g++) {
                    f16x8 bf = *(const f16x8*)&Blds[((kt * 4 + kc) * 96 + g * 32 + col) * 8];
                    acc[g][0] = __builtin_amdgcn_mfma_f32_32x32x16_f16(af0, bf, acc[g][0], 0, 0, 0);
                    acc[g][1] = __builtin_amdgcn_mfma_f32_32x32x16_f16(af1, bf, acc[g][1], 0, 0, 0);
                }
            }
            __builtin_amdgcn_s_setprio(0);
            __builtin_amdgcn_sched_barrier(0);
            __builtin_amdgcn_s_barrier();
            if (kt < 14) stage(cur, kt + 2);
            cur ^= 1;
        }

        // epilogue: gates + h update + decoder partial
        #pragma unroll
        for (int mi = 0; mi < 2; mi++) {
            #pragma unroll
            for (int r = 0; r < 16; r++) {
                int m = m0 + wid * 64 + mi * 32 + (r & 3) + 8 * (r >> 2) + 4 * half;
                float prev = (t > 0) ? out[(size_t)m * TSTEP + t - 1] : 0.f;
                float hp = (float)hin[(size_t)(e >> 3) * 32768 + m * 8 + (e & 7)];
                float gr = acc[0][mi][r] + bhr + fmaf(prev, wir, bir);
                float gz = acc[1][mi][r] + bhz + fmaf(prev, wiz, biz);
                float gn = fmaf(prev, win, bin_);
                float rr = sigmoid_fast(gr), zz = sigmoid_fast(gz);
                float nn = tanh_fast(fmaf(rr, acc[2][mi][r] + bhn, gn));
                float hn = fmaf(zz, hp - nn, nn);        // (1-z)n + z*hp
                hout[(size_t)(e >> 3) * 32768 + m * 8 + (e & 7)] = (f16)hn;
                float v = hn * dw;
                v += __shfl_xor(v, 1);  v += __shfl_xor(v, 2);
                v += __shfl_xor(v, 4);  v += __shfl_xor(v, 8);
                v += __shfl_xor(v, 16);
                if (col == 0) atomicAdd(&out[(size_t)m * TSTEP + t], v);
            }
        }

        __threadfence();                   // release: publish hout + out[:,t]
        __syncthreads();
        if (tid == 0)
            __hip_atomic_fetch_add(&bar[vbar + t], 1, __ATOMIC_RELEASE,
                                   __HIP_MEMORY_SCOPE_AGENT);
    }
}

extern "C" void kernel_launch(void* const* d_in, const int* in_sizes, int n_in,
                              void* d_out, int out_size, void* d_ws, size_t ws_size,
                              hipStream_t stream)
{
    const float* x      = (const float*)d_in[0];
    const float* conv_w = (const float*)d_in[1];
    const float* conv_b = (const float*)d_in[2];
    const float* fc_w   = (const float*)d_in[3];
    const float* fc_b   = (const float*)d_in[4];
    const float* w_ih   = (const float*)d_in[5];
    const float* b_ih   = (const float*)d_in[6];
    const float* w_hh   = (const float*)d_in[7];
    const float* b_hh   = (const float*)d_in[8];
    const float* dec_w  = (const float*)d_in[9];
    const float* dec_b  = (const float*)d_in[10];
    float* out = (float*)d_out;

    char* ws = (char*)d_ws;
    // layout (bytes):
    //   [0,         9437184)   convbuf16 [4096][1152] f16
    //   [9437184,  13631488)   h16_a  (k-major [64][4096][8])
    //   [13631488, 17825792)   h16_b  (k-major)
    //   [17825792, 19398656)   w16T   [64][1536][8] f16
    //   [19398656, 19435520)   w16c   [9][32][64] swizzled
    //   [19435520, 20615168)   fcp16  [512][1152] permuted
    //   [20615168, 20619264)   bar    [16][64] int
    f16*  convbuf16 = (f16*)ws;
    f16*  h16_a     = (f16*)(ws + 9437184);
    f16*  h16_b     = (f16*)(ws + 13631488);
    f16*  w16T      = (f16*)(ws + 17825792);
    f16*  w16c      = (f16*)(ws + 19398656);
    f16*  fcp16     = (f16*)(ws + 19435520);
    int*  bar       = (int*)(ws + 20615168);

    int prep_n = G3 * EMB + 9 * 32 * 64 + EMB * KFC + B_ * TSTEP + 1024;
    prep_kernel<<<(prep_n + 255) / 256, 256, 0, stream>>>(
        w_hh, w16T, conv_w, w16c, fc_w, fcp16, dec_b, out, bar);

    conv_mfma<<<B_ / 8, 256, 0, stream>>>(x, w16c, conv_b, convbuf16);
    fc_mfma<<<dim3(EMB / 64, B_ / 64), 256, 0, stream>>>(convbuf16, fcp16, fc_b, h16_a);

    gru_persist<<<256, 256, 0, stream>>>(
        h16_a, h16_b, w16T, b_hh, w_ih, b_ih, dec_w, out, bar);
}

// Round 8
// 1088.559 us; speedup vs baseline: 3.8418x; 3.8418x over previous
//
#include <hip/hip_runtime.h>
#include <math.h>

#define B_    4096
#define CIN   60
#define CW    32
#define EMB   512
#define TSTEP 50
#define KFC   1152   // 36*32 (pos-major, co-minor layout!)
#define G3    1536

typedef _Float16 f16;
typedef _Float16 f16x4 __attribute__((ext_vector_type(4)));
typedef _Float16 f16x8 __attribute__((ext_vector_type(8)));
typedef float    f32x4 __attribute__((ext_vector_type(4)));
typedef float    f32x16 __attribute__((ext_vector_type(16)));

typedef __attribute__((address_space(3))) void       lds_void_t;
typedef __attribute__((address_space(1))) const void g_void_t;

__device__ __forceinline__ float sigmoid_fast(float x){ return 1.f/(1.f+__expf(-x)); }
__device__ __forceinline__ float tanh_fast(float x){ float e=__expf(2.f*x); return 1.f-2.f/(e+1.f); }

// ---------- fused weight prep ----------
// w_hh -> w16T [64 kc][1536 R][8] f16 (k-major);  conv_w -> w16c swizzled;
// fc_w -> fcp16 permuted;  out init.
__global__ void prep_kernel(const float* __restrict__ w_hh, f16* __restrict__ w16T,
                            const float* __restrict__ conv_w, f16* __restrict__ w16c,
                            const float* __restrict__ fc_w, f16* __restrict__ fcp16,
                            const float* __restrict__ dec_b, float* __restrict__ out)
{
    int i = blockIdx.x * 256 + threadIdx.x;
    if (i < G3 * EMB) {
        int R = i >> 9, k = i & 511;
        w16T[(size_t)(k >> 3) * 12288 + R * 8 + (k & 7)] = (f16)w_hh[i];
        return;
    }
    i -= G3 * EMB;
    if (i < 9 * 32 * 64) {
        int khkw = i >> 11, r = i & 2047, co = r >> 6, ci = r & 63;
        float v = (ci < CIN) ? conv_w[(co * CIN + ci) * 9 + khkw] : 0.f;
        int dst = khkw * 2048 + co * 64 + (((ci >> 3) ^ (co & 7)) << 3) + (ci & 7);
        w16c[dst] = (f16)v;
        return;
    }
    i -= 9 * 32 * 64;
    if (i < EMB * KFC) {
        int e = i / KFC, j = i % KFC;
        int co = j & 31, pos = j >> 5;
        fcp16[i] = (f16)fc_w[e * KFC + co * 36 + pos];
        return;
    }
    i -= EMB * KFC;
    if (i < B_ * TSTEP) out[i] = dec_b[0];
}

// ---------- conv 3x3 VALID + relu via im2col MFMA, weights in registers ----------
__global__ __launch_bounds__(256) void conv_mfma(
    const float* __restrict__ x, const f16* __restrict__ w16c,
    const float* __restrict__ conv_b, f16* __restrict__ outc)
{
    __shared__ __align__(16) f16 xt[8 * 64 * 64];    // 64 KB
    int tid = threadIdx.x, wid = tid >> 6, lane = tid & 63;
    int b0 = blockIdx.x * 8;
    int mhalf = wid >> 1, nt = wid & 1;
    int lrow = lane & 15, kgrp = lane >> 4;
    int co = nt * 16 + lrow;

    f16x8 bfr[18];
    #pragma unroll
    for (int ks = 0; ks < 18; ks++) {
        int khkw = ks >> 1, c = (ks & 1) * 4 + kgrp;
        bfr[ks] = *(const f16x8*)((const char*)w16c +
                    khkw * 4096 + co * 128 + ((c ^ (co & 7)) << 4));
    }
    float cb = conv_b[co];

    #pragma unroll
    for (int bt = 0; bt < 3; bt++) {
        float ra[10][4];
        #pragma unroll
        for (int j = 0; j < 10; j++) {
            int idx = (bt * 10 + j) * 4 + wid;
            int img = idx / 15, cq = idx - img * 15;
            const float* xp = x + ((size_t)(b0 + img) * CIN + cq * 4) * 64 + lane;
            ra[j][0] = xp[0]; ra[j][1] = xp[64]; ra[j][2] = xp[128]; ra[j][3] = xp[192];
        }
        #pragma unroll
        for (int j = 0; j < 10; j++) {
            int idx = (bt * 10 + j) * 4 + wid;
            int img = idx / 15, cq = idx - img * 15;
            f16x4 v = { (f16)ra[j][0], (f16)ra[j][1], (f16)ra[j][2], (f16)ra[j][3] };
            int off = img * 8192 + lane * 128 + (((cq >> 1) ^ (lane & 7)) << 4) + (cq & 1) * 8;
            *(f16x4*)((char*)xt + off) = v;
        }
    }
    #pragma unroll
    for (int i = 0; i < 2; i++) {
        int s = i * 256 + tid, img = s >> 6, px = s & 63;
        int off = img * 8192 + px * 128 + ((7 ^ (px & 7)) << 4) + 8;
        *(f16x4*)((char*)xt + off) = f16x4{0, 0, 0, 0};
    }
    __syncthreads();

    int imgs[9], pxb[9];
    #pragma unroll
    for (int i = 0; i < 9; i++) {
        int row = mhalf * 144 + i * 16 + lrow;
        int img = (row * 1821) >> 16, pos = row - img * 36;
        int oh = (pos * 43) >> 8, ow = pos - oh * 6;
        imgs[i] = img; pxb[i] = oh * 8 + ow;
    }

    f32x4 acc[9];
    #pragma unroll
    for (int i = 0; i < 9; i++) acc[i] = f32x4{0, 0, 0, 0};

    #pragma unroll
    for (int ks = 0; ks < 18; ks++) {
        int khkw = ks >> 1;
        int kh = khkw / 3, kw = khkw - kh * 3;
        int c = (ks & 1) * 4 + kgrp;
        #pragma unroll
        for (int i = 0; i < 9; i++) {
            int px = pxb[i] + kh * 8 + kw;
            f16x8 af = *(const f16x8*)((const char*)xt +
                         imgs[i] * 8192 + px * 128 + ((c ^ (px & 7)) << 4));
            acc[i] = __builtin_amdgcn_mfma_f32_16x16x32_f16(af, bfr[ks], acc[i], 0, 0, 0);
        }
    }

    #pragma unroll
    for (int i = 0; i < 9; i++) {
        #pragma unroll
        for (int j = 0; j < 4; j++) {
            int row = mhalf * 144 + i * 16 + kgrp * 4 + j;
            int img = (row * 1821) >> 16, pos = row - img * 36;
            float v = fmaxf(acc[i][j] + cb, 0.f);
            outc[(size_t)(b0 + img) * KFC + pos * 32 + co] = (f16)v;
        }
    }
}

// ---------- FC: f16 MFMA GEMM, relu -> h16T [64 kc][4096 m][8] ----------
__global__ __launch_bounds__(256) void fc_mfma(
    const f16* __restrict__ A, const f16* __restrict__ Bm,
    const float* __restrict__ bias, f16* __restrict__ h16T)
{
    __shared__ __align__(16) f16 As[2][64 * 64];
    __shared__ __align__(16) f16 Bs[2][64 * 64];
    int tid = threadIdx.x, wid = tid >> 6, lane = tid & 63;
    int wr = wid >> 1, wc = wid & 1;
    int col = lane & 31, half = lane >> 5;
    int m0 = blockIdx.y * 64, n0 = blockIdx.x * 64;

    const f16* gA[2]; const f16* gB[2];
    #pragma unroll
    for (int i = 0; i < 2; i++) {
        int q = i * 256 + tid, row = q >> 3, cp = q & 7, c = cp ^ (row & 7);
        gA[i] = A  + (size_t)(m0 + row) * KFC + c * 8;
        gB[i] = Bm + (size_t)(n0 + row) * KFC + c * 8;
    }
    auto stage = [&](int buf, int k0) {
        #pragma unroll
        for (int i = 0; i < 2; i++)
            __builtin_amdgcn_global_load_lds((const g_void_t*)(gA[i] + k0),
                (lds_void_t*)((char*)&As[buf][0] + (i * 256 + wid * 64) * 16), 16, 0, 0);
        #pragma unroll
        for (int i = 0; i < 2; i++)
            __builtin_amdgcn_global_load_lds((const g_void_t*)(gB[i] + k0),
                (lds_void_t*)((char*)&Bs[buf][0] + (i * 256 + wid * 64) * 16), 16, 0, 0);
    };

    f32x16 acc;
    #pragma unroll
    for (int r = 0; r < 16; r++) acc[r] = 0.f;

    stage(0, 0); stage(1, 64);
    int cur = 0, arow = wr * 32 + col, brow = wc * 32 + col;
    #pragma unroll 1
    for (int kt = 0; kt < 17; kt++) {
        asm volatile("s_waitcnt vmcnt(4)" ::: "memory");
        __builtin_amdgcn_s_barrier();
        __builtin_amdgcn_sched_barrier(0);
        __builtin_amdgcn_s_setprio(1);
        #pragma unroll
        for (int kk = 0; kk < 4; kk++) {
            int ch = kk * 2 + half;
            f16x8 af = *(const f16x8*)&As[cur][arow * 64 + ((ch ^ (arow & 7)) << 3)];
            f16x8 bf = *(const f16x8*)&Bs[cur][brow * 64 + ((ch ^ (brow & 7)) << 3)];
            acc = __builtin_amdgcn_mfma_f32_32x32x16_f16(af, bf, acc, 0, 0, 0);
        }
        __builtin_amdgcn_s_setprio(0);
        __builtin_amdgcn_sched_barrier(0);
        __builtin_amdgcn_s_barrier();
        if (kt < 16) stage(cur, (kt + 2) * 64);
        cur ^= 1;
    }
    asm volatile("s_waitcnt vmcnt(0)" ::: "memory");
    __builtin_amdgcn_s_barrier();
    __builtin_amdgcn_sched_barrier(0);
    #pragma unroll
    for (int kk = 0; kk < 4; kk++) {
        int ch = kk * 2 + half;
        f16x8 af = *(const f16x8*)&As[cur][arow * 64 + ((ch ^ (arow & 7)) << 3)];
        f16x8 bf = *(const f16x8*)&Bs[cur][brow * 64 + ((ch ^ (brow & 7)) << 3)];
        acc = __builtin_amdgcn_mfma_f32_32x32x16_f16(af, bf, acc, 0, 0, 0);
    }

    #pragma unroll
    for (int r = 0; r < 16; r++) {
        int m = m0 + wr * 32 + (r & 3) + 8 * (r >> 2) + 4 * half;
        int n = n0 + wc * 32 + col;
        float v = fmaxf(acc[r] + bias[n], 0.f);
        h16T[(size_t)(n >> 3) * 32768 + m * 8 + (n & 7)] = (f16)v;
    }
}

// ---------- per-launch GRU step v3: 128m x 64e x 3g block, mf=2 waves ----------
// 256 blocks x 256 thr (4 waves: wr = m-half, wc = e-half; wave 64m x 96n).
// k-major h/W: coalesced gload_lds (linear dest) + conflict-free ds_read_b128.
// LDS 80KB dbuf, 8 phases of K=64, counted vmcnt(10).
// XCD swizzle: XCD owns 4 m-groups x all 8 e-groups -> W(1.5MB)+h-slice(0.5MB) L2-hot.
__global__ __launch_bounds__(256, 1) void gru_step(
    const f16* __restrict__ hin, f16* __restrict__ hout,
    const f16* __restrict__ w16T, const float* __restrict__ b_hh,
    const float* __restrict__ w_ih, const float* __restrict__ b_ih,
    const float* __restrict__ dec_w, float* __restrict__ out, int t)
{
    __shared__ __align__(16) f16 Alds[2][8 * 128 * 8];   // 2 x 16 KB
    __shared__ __align__(16) f16 Blds[2][8 * 192 * 8];   // 2 x 24 KB
    int tid = threadIdx.x, wid = tid >> 6, lane = tid & 63;
    int wr = wid >> 1, wc = wid & 1;
    int col = lane & 31, half = lane >> 5;

    int xc = blockIdx.x & 7, rb = blockIdx.x >> 3;
    int mg = xc * 4 + (rb & 3), eg = rb >> 2;       // 32 mg x 8 eg
    int m0 = mg * 128, e0 = eg * 64;
    int e  = e0 + wc * 32 + col;

    // epilogue operand preload (latency hides under the GEMM)
    float wir = w_ih[e], wiz = w_ih[EMB + e], win = w_ih[2 * EMB + e];
    float bir = b_ih[e], biz = b_ih[EMB + e], bin_ = b_ih[2 * EMB + e];
    float bhr = b_hh[e], bhz = b_hh[EMB + e], bhn = b_hh[2 * EMB + e];
    float dw  = dec_w[e];
    int tprev = (t > 0) ? t - 1 : 0;
    float prevv[2][16], hpv[2][16];
    #pragma unroll
    for (int mi = 0; mi < 2; mi++)
        #pragma unroll
        for (int r = 0; r < 16; r++) {
            int m = m0 + wr * 64 + mi * 32 + (r & 3) + 8 * (r >> 2) + 4 * half;
            float pv = out[(size_t)m * TSTEP + tprev];
            prevv[mi][r] = (t > 0) ? pv : 0.f;
            hpv[mi][r]   = (float)hin[(size_t)(e >> 3) * 32768 + m * 8 + (e & 7)];
        }

    // staging source addresses
    const f16* gA[4]; const f16* gB[6];
    #pragma unroll
    for (int i = 0; i < 4; i++) {
        int q = i * 256 + tid, kc = q >> 7, m = q & 127;
        gA[i] = hin + (size_t)kc * 32768 + (m0 + m) * 8;
    }
    #pragma unroll
    for (int i = 0; i < 6; i++) {
        int q = i * 256 + tid, kc = q / 192, row = q - kc * 192;
        int g = row >> 6, c = row & 63;
        gB[i] = w16T + (size_t)kc * 12288 + (g * 512 + e0 + c) * 8;
    }
    auto stage = [&](int buf, int kt) {
        #pragma unroll
        for (int i = 0; i < 4; i++)
            __builtin_amdgcn_global_load_lds(
                (const g_void_t*)(gA[i] + (size_t)kt * 8 * 32768),
                (lds_void_t*)((char*)&Alds[buf][0] + (i * 256 + wid * 64) * 16), 16, 0, 0);
        #pragma unroll
        for (int i = 0; i < 6; i++)
            __builtin_amdgcn_global_load_lds(
                (const g_void_t*)(gB[i] + (size_t)kt * 8 * 12288),
                (lds_void_t*)((char*)&Blds[buf][0] + (i * 256 + wid * 64) * 16), 16, 0, 0);
    };

    f32x16 acc[3][2];
    #pragma unroll
    for (int g = 0; g < 3; g++)
        #pragma unroll
        for (int mi = 0; mi < 2; mi++)
            #pragma unroll
            for (int r = 0; r < 16; r++) acc[g][mi][r] = 0.f;

    stage(0, 0); stage(1, 1);
    int cur = 0;
    #pragma unroll 1
    for (int kt = 0; kt < 8; kt++) {
        if (kt < 7) asm volatile("s_waitcnt vmcnt(10)" ::: "memory");
        else        asm volatile("s_waitcnt vmcnt(0)" ::: "memory");
        __builtin_amdgcn_s_barrier();
        __builtin_amdgcn_sched_barrier(0);
        __builtin_amdgcn_s_setprio(1);
        #pragma unroll
        for (int kk = 0; kk < 4; kk++) {
            int kc = kk * 2 + half;
            f16x8 af0 = *(const f16x8*)&Alds[cur][(kc * 128 + wr * 64 + col) * 8];
            f16x8 af1 = *(const f16x8*)&Alds[cur][(kc * 128 + wr * 64 + 32 + col) * 8];
            #pragma unroll
            for (int g = 0; g < 3; g++) {
                f16x8 bf = *(const f16x8*)&Blds[cur][(kc * 192 + g * 64 + wc * 32 + col) * 8];
                acc[g][0] = __builtin_amdgcn_mfma_f32_32x32x16_f16(af0, bf, acc[g][0], 0, 0, 0);
                acc[g][1] = __builtin_amdgcn_mfma_f32_32x32x16_f16(af1, bf, acc[g][1], 0, 0, 0);
            }
        }
        __builtin_amdgcn_s_setprio(0);
        __builtin_amdgcn_sched_barrier(0);
        __builtin_amdgcn_s_barrier();
        if (kt < 6) stage(cur, kt + 2);
        cur ^= 1;
    }

    // epilogue: gates + h update + decoder partial
    #pragma unroll
    for (int mi = 0; mi < 2; mi++) {
        #pragma unroll
        for (int r = 0; r < 16; r++) {
            int m = m0 + wr * 64 + mi * 32 + (r & 3) + 8 * (r >> 2) + 4 * half;
            float prev = prevv[mi][r];
            float gr = acc[0][mi][r] + bhr + fmaf(prev, wir, bir);
            float gz = acc[1][mi][r] + bhz + fmaf(prev, wiz, biz);
            float gn = fmaf(prev, win, bin_);
            float rr = sigmoid_fast(gr), zz = sigmoid_fast(gz);
            float nn = tanh_fast(fmaf(rr, acc[2][mi][r] + bhn, gn));
            float hn = fmaf(zz, hpv[mi][r] - nn, nn);        // (1-z)n + z*hp
            hout[(size_t)(e >> 3) * 32768 + m * 8 + (e & 7)] = (f16)hn;
            float v = hn * dw;
            v += __shfl_xor(v, 1);  v += __shfl_xor(v, 2);
            v += __shfl_xor(v, 4);  v += __shfl_xor(v, 8);
            v += __shfl_xor(v, 16);
            if (col == 0) atomicAdd(&out[(size_t)m * TSTEP + t], v);
        }
    }
}

extern "C" void kernel_launch(void* const* d_in, const int* in_sizes, int n_in,
                              void* d_out, int out_size, void* d_ws, size_t ws_size,
                              hipStream_t stream)
{
    const float* x      = (const float*)d_in[0];
    const float* conv_w = (const float*)d_in[1];
    const float* conv_b = (const float*)d_in[2];
    const float* fc_w   = (const float*)d_in[3];
    const float* fc_b   = (const float*)d_in[4];
    const float* w_ih   = (const float*)d_in[5];
    const float* b_ih   = (const float*)d_in[6];
    const float* w_hh   = (const float*)d_in[7];
    const float* b_hh   = (const float*)d_in[8];
    const float* dec_w  = (const float*)d_in[9];
    const float* dec_b  = (const float*)d_in[10];
    float* out = (float*)d_out;

    char* ws = (char*)d_ws;
    // layout (bytes):
    //   [0,         9437184)   convbuf16 [4096][1152] f16
    //   [9437184,  13631488)   h16_a  (k-major [64][4096][8])
    //   [13631488, 17825792)   h16_b  (k-major)
    //   [17825792, 19398656)   w16T   [64][1536][8] f16
    //   [19398656, 19435520)   w16c   [9][32][64] swizzled
    //   [19435520, 20615168)   fcp16  [512][1152] permuted
    f16*  convbuf16 = (f16*)ws;
    f16*  h16_a     = (f16*)(ws + 9437184);
    f16*  h16_b     = (f16*)(ws + 13631488);
    f16*  w16T      = (f16*)(ws + 17825792);
    f16*  w16c      = (f16*)(ws + 19398656);
    f16*  fcp16     = (f16*)(ws + 19435520);

    int prep_n = G3 * EMB + 9 * 32 * 64 + EMB * KFC + B_ * TSTEP;
    prep_kernel<<<(prep_n + 255) / 256, 256, 0, stream>>>(
        w_hh, w16T, conv_w, w16c, fc_w, fcp16, dec_b, out);

    conv_mfma<<<B_ / 8, 256, 0, stream>>>(x, w16c, conv_b, convbuf16);
    fc_mfma<<<dim3(EMB / 64, B_ / 64), 256, 0, stream>>>(convbuf16, fcp16, fc_b, h16_a);

    for (int t = 0; t < TSTEP; t++) {
        const f16* hi = (t & 1) ? h16_b : h16_a;
        f16*       ho = (t & 1) ? h16_a : h16_b;
        gru_step<<<256, 256, 0, stream>>>(
            hi, ho, w16T, b_hh, w_ih, b_ih, dec_w, out, t);
    }
}

// Round 9
// 808.556 us; speedup vs baseline: 5.1723x; 1.3463x over previous
//
#include <hip/hip_runtime.h>
#include <math.h>

#define B_    4096
#define CIN   60
#define CW    32
#define EMB   512
#define TSTEP 50
#define KFC   1152   // 36*32 (pos-major, co-minor layout!)
#define G3    1536

typedef _Float16 f16;
typedef _Float16 f16x4 __attribute__((ext_vector_type(4)));
typedef _Float16 f16x8 __attribute__((ext_vector_type(8)));
typedef float    f32x4 __attribute__((ext_vector_type(4)));
typedef float    f32x16 __attribute__((ext_vector_type(16)));

typedef __attribute__((address_space(3))) void       lds_void_t;
typedef __attribute__((address_space(1))) const void g_void_t;

__device__ __forceinline__ float sigmoid_fast(float x){ return 1.f/(1.f+__expf(-x)); }
__device__ __forceinline__ float tanh_fast(float x){ float e=__expf(2.f*x); return 1.f-2.f/(e+1.f); }

// ---------- fused weight prep ----------
__global__ void prep_kernel(const float* __restrict__ w_hh, f16* __restrict__ w16T,
                            const float* __restrict__ conv_w, f16* __restrict__ w16c,
                            const float* __restrict__ fc_w, f16* __restrict__ fcp16,
                            const float* __restrict__ dec_b, float* __restrict__ out)
{
    int i = blockIdx.x * 256 + threadIdx.x;
    if (i < G3 * EMB) {
        int R = i >> 9, k = i & 511;
        w16T[(size_t)(k >> 3) * 12288 + R * 8 + (k & 7)] = (f16)w_hh[i];
        return;
    }
    i -= G3 * EMB;
    if (i < 9 * 32 * 64) {
        int khkw = i >> 11, r = i & 2047, co = r >> 6, ci = r & 63;
        float v = (ci < CIN) ? conv_w[(co * CIN + ci) * 9 + khkw] : 0.f;
        int dst = khkw * 2048 + co * 64 + (((ci >> 3) ^ (co & 7)) << 3) + (ci & 7);
        w16c[dst] = (f16)v;
        return;
    }
    i -= 9 * 32 * 64;
    if (i < EMB * KFC) {
        int e = i / KFC, j = i % KFC;
        int co = j & 31, pos = j >> 5;
        fcp16[i] = (f16)fc_w[e * KFC + co * 36 + pos];
        return;
    }
    i -= EMB * KFC;
    if (i < B_ * TSTEP) out[i] = dec_b[0];
}

// ---------- conv 3x3 VALID + relu via im2col MFMA, weights in registers ----------
__global__ __launch_bounds__(256) void conv_mfma(
    const float* __restrict__ x, const f16* __restrict__ w16c,
    const float* __restrict__ conv_b, f16* __restrict__ outc)
{
    __shared__ __align__(16) f16 xt[8 * 64 * 64];    // 64 KB
    int tid = threadIdx.x, wid = tid >> 6, lane = tid & 63;
    int b0 = blockIdx.x * 8;
    int mhalf = wid >> 1, nt = wid & 1;
    int lrow = lane & 15, kgrp = lane >> 4;
    int co = nt * 16 + lrow;

    f16x8 bfr[18];
    #pragma unroll
    for (int ks = 0; ks < 18; ks++) {
        int khkw = ks >> 1, c = (ks & 1) * 4 + kgrp;
        bfr[ks] = *(const f16x8*)((const char*)w16c +
                    khkw * 4096 + co * 128 + ((c ^ (co & 7)) << 4));
    }
    float cb = conv_b[co];

    #pragma unroll
    for (int bt = 0; bt < 3; bt++) {
        float ra[10][4];
        #pragma unroll
        for (int j = 0; j < 10; j++) {
            int idx = (bt * 10 + j) * 4 + wid;
            int img = idx / 15, cq = idx - img * 15;
            const float* xp = x + ((size_t)(b0 + img) * CIN + cq * 4) * 64 + lane;
            ra[j][0] = xp[0]; ra[j][1] = xp[64]; ra[j][2] = xp[128]; ra[j][3] = xp[192];
        }
        #pragma unroll
        for (int j = 0; j < 10; j++) {
            int idx = (bt * 10 + j) * 4 + wid;
            int img = idx / 15, cq = idx - img * 15;
            f16x4 v = { (f16)ra[j][0], (f16)ra[j][1], (f16)ra[j][2], (f16)ra[j][3] };
            int off = img * 8192 + lane * 128 + (((cq >> 1) ^ (lane & 7)) << 4) + (cq & 1) * 8;
            *(f16x4*)((char*)xt + off) = v;
        }
    }
    #pragma unroll
    for (int i = 0; i < 2; i++) {
        int s = i * 256 + tid, img = s >> 6, px = s & 63;
        int off = img * 8192 + px * 128 + ((7 ^ (px & 7)) << 4) + 8;
        *(f16x4*)((char*)xt + off) = f16x4{0, 0, 0, 0};
    }
    __syncthreads();

    int imgs[9], pxb[9];
    #pragma unroll
    for (int i = 0; i < 9; i++) {
        int row = mhalf * 144 + i * 16 + lrow;
        int img = (row * 1821) >> 16, pos = row - img * 36;
        int oh = (pos * 43) >> 8, ow = pos - oh * 6;
        imgs[i] = img; pxb[i] = oh * 8 + ow;
    }

    f32x4 acc[9];
    #pragma unroll
    for (int i = 0; i < 9; i++) acc[i] = f32x4{0, 0, 0, 0};

    #pragma unroll
    for (int ks = 0; ks < 18; ks++) {
        int khkw = ks >> 1;
        int kh = khkw / 3, kw = khkw - kh * 3;
        int c = (ks & 1) * 4 + kgrp;
        #pragma unroll
        for (int i = 0; i < 9; i++) {
            int px = pxb[i] + kh * 8 + kw;
            f16x8 af = *(const f16x8*)((const char*)xt +
                         imgs[i] * 8192 + px * 128 + ((c ^ (px & 7)) << 4));
            acc[i] = __builtin_amdgcn_mfma_f32_16x16x32_f16(af, bfr[ks], acc[i], 0, 0, 0);
        }
    }

    #pragma unroll
    for (int i = 0; i < 9; i++) {
        #pragma unroll
        for (int j = 0; j < 4; j++) {
            int row = mhalf * 144 + i * 16 + kgrp * 4 + j;
            int img = (row * 1821) >> 16, pos = row - img * 36;
            float v = fmaxf(acc[i][j] + cb, 0.f);
            outc[(size_t)(b0 + img) * KFC + pos * 32 + co] = (f16)v;
        }
    }
}

// ---------- FC: f16 MFMA GEMM, relu -> h16T [64 kc][4096 m][8] ----------
__global__ __launch_bounds__(256) void fc_mfma(
    const f16* __restrict__ A, const f16* __restrict__ Bm,
    const float* __restrict__ bias, f16* __restrict__ h16T)
{
    __shared__ __align__(16) f16 As[2][64 * 64];
    __shared__ __align__(16) f16 Bs[2][64 * 64];
    int tid = threadIdx.x, wid = tid >> 6, lane = tid & 63;
    int wr = wid >> 1, wc = wid & 1;
    int col = lane & 31, half = lane >> 5;
    int m0 = blockIdx.y * 64, n0 = blockIdx.x * 64;

    const f16* gA[2]; const f16* gB[2];
    #pragma unroll
    for (int i = 0; i < 2; i++) {
        int q = i * 256 + tid, row = q >> 3, cp = q & 7, c = cp ^ (row & 7);
        gA[i] = A  + (size_t)(m0 + row) * KFC + c * 8;
        gB[i] = Bm + (size_t)(n0 + row) * KFC + c * 8;
    }
    auto stage = [&](int buf, int k0) {
        #pragma unroll
        for (int i = 0; i < 2; i++)
            __builtin_amdgcn_global_load_lds((const g_void_t*)(gA[i] + k0),
                (lds_void_t*)((char*)&As[buf][0] + (i * 256 + wid * 64) * 16), 16, 0, 0);
        #pragma unroll
        for (int i = 0; i < 2; i++)
            __builtin_amdgcn_global_load_lds((const g_void_t*)(gB[i] + k0),
                (lds_void_t*)((char*)&Bs[buf][0] + (i * 256 + wid * 64) * 16), 16, 0, 0);
    };

    f32x16 acc;
    #pragma unroll
    for (int r = 0; r < 16; r++) acc[r] = 0.f;

    stage(0, 0); stage(1, 64);
    int cur = 0, arow = wr * 32 + col, brow = wc * 32 + col;
    #pragma unroll 1
    for (int kt = 0; kt < 17; kt++) {
        asm volatile("s_waitcnt vmcnt(4)" ::: "memory");
        __builtin_amdgcn_s_barrier();
        __builtin_amdgcn_sched_barrier(0);
        __builtin_amdgcn_s_setprio(1);
        #pragma unroll
        for (int kk = 0; kk < 4; kk++) {
            int ch = kk * 2 + half;
            f16x8 af = *(const f16x8*)&As[cur][arow * 64 + ((ch ^ (arow & 7)) << 3)];
            f16x8 bf = *(const f16x8*)&Bs[cur][brow * 64 + ((ch ^ (brow & 7)) << 3)];
            acc = __builtin_amdgcn_mfma_f32_32x32x16_f16(af, bf, acc, 0, 0, 0);
        }
        __builtin_amdgcn_s_setprio(0);
        __builtin_amdgcn_sched_barrier(0);
        __builtin_amdgcn_s_barrier();
        if (kt < 16) stage(cur, (kt + 2) * 64);
        cur ^= 1;
    }
    asm volatile("s_waitcnt vmcnt(0)" ::: "memory");
    __builtin_amdgcn_s_barrier();
    __builtin_amdgcn_sched_barrier(0);
    #pragma unroll
    for (int kk = 0; kk < 4; kk++) {
        int ch = kk * 2 + half;
        f16x8 af = *(const f16x8*)&As[cur][arow * 64 + ((ch ^ (arow & 7)) << 3)];
        f16x8 bf = *(const f16x8*)&Bs[cur][brow * 64 + ((ch ^ (brow & 7)) << 3)];
        acc = __builtin_amdgcn_mfma_f32_32x32x16_f16(af, bf, acc, 0, 0, 0);
    }

    #pragma unroll
    for (int r = 0; r < 16; r++) {
        int m = m0 + wr * 32 + (r & 3) + 8 * (r >> 2) + 4 * half;
        int n = n0 + wc * 32 + col;
        float v = fmaxf(acc[r] + bias[n], 0.f);
        h16T[(size_t)(n >> 3) * 32768 + m * 8 + (n & 7)] = (f16)v;
    }
}

// ---------- GRU step v4: 64m x 64e x 3g, 4 waves, 2 blocks/CU (8 waves/CU) ----------
// 512 blocks x 256 thr. LDS 64KB -> 2 blocks/CU; __launch_bounds__(256,2).
// k-major h/W: coalesced gload_lds (linear dest) + conflict-free ds_read_b128.
// Counted vmcnt(8) depth-2. XCD: each XCD = 8 mg x 8 eg -> W + h-slice L2-hot.
__global__ __launch_bounds__(256, 2) void gru_step(
    const f16* __restrict__ hin, f16* __restrict__ hout,
    const f16* __restrict__ w16T, const float* __restrict__ b_hh,
    const float* __restrict__ w_ih, const float* __restrict__ b_ih,
    const float* __restrict__ dec_w, float* __restrict__ out, int t)
{
    __shared__ __align__(16) f16 Alds[2][8 * 64 * 8];    // 2 x 8 KB
    __shared__ __align__(16) f16 Blds[2][8 * 192 * 8];   // 2 x 24 KB
    int tid = threadIdx.x, wid = tid >> 6, lane = tid & 63;
    int wr = wid >> 1, wc = wid & 1;
    int col = lane & 31, half = lane >> 5;

    int xc = blockIdx.x & 7, rb = blockIdx.x >> 3;       // rb 0..63
    int mg = xc * 8 + (rb & 7), eg = rb >> 3;            // 64 mg x 8 eg
    int m0 = mg * 64, e0 = eg * 64;
    int e  = e0 + wc * 32 + col;

    // hoisted epilogue operands (issue first -> oldest in vmcnt queue)
    float wir = w_ih[e], wiz = w_ih[EMB + e], win = w_ih[2 * EMB + e];
    float bir = b_ih[e], biz = b_ih[EMB + e], bin_ = b_ih[2 * EMB + e];
    float bhr = b_hh[e], bhz = b_hh[EMB + e], bhn = b_hh[2 * EMB + e];
    float dw  = dec_w[e];
    int tprev = (t > 0) ? t - 1 : 0;
    float prevv[16], hpv[16];
    #pragma unroll
    for (int r = 0; r < 16; r++) {
        int m = m0 + wr * 32 + (r & 3) + 8 * (r >> 2) + 4 * half;
        float pv = out[(size_t)m * TSTEP + tprev];       // lane-uniform per half -> broadcast
        prevv[r] = (t > 0) ? pv : 0.f;
        hpv[r]   = (float)hin[(size_t)(e >> 3) * 32768 + m * 8 + (e & 7)];
    }

    // staging source addresses (A: 2 loads/stage, B: 6 loads/stage = 8 total)
    const f16* gA[2]; const f16* gB[6];
    #pragma unroll
    for (int i = 0; i < 2; i++) {
        int cell = i * 256 + tid, kc = cell >> 6, m = cell & 63;
        gA[i] = hin + (size_t)kc * 32768 + (m0 + m) * 8;
    }
    #pragma unroll
    for (int i = 0; i < 6; i++) {
        int cell = i * 256 + tid, kc = cell / 192, row = cell - kc * 192;
        int g = row >> 6, c = row & 63;
        gB[i] = w16T + (size_t)kc * 12288 + (g * 512 + e0 + c) * 8;
    }
    auto stage = [&](int buf, int kt) {
        #pragma unroll
        for (int i = 0; i < 2; i++)
            __builtin_amdgcn_global_load_lds(
                (const g_void_t*)(gA[i] + (size_t)kt * 8 * 32768),
                (lds_void_t*)((char*)&Alds[buf][0] + (i * 256 + wid * 64) * 16), 16, 0, 0);
        #pragma unroll
        for (int i = 0; i < 6; i++)
            __builtin_amdgcn_global_load_lds(
                (const g_void_t*)(gB[i] + (size_t)kt * 8 * 12288),
                (lds_void_t*)((char*)&Blds[buf][0] + (i * 256 + wid * 64) * 16), 16, 0, 0);
    };

    f32x16 acc[3];
    #pragma unroll
    for (int g = 0; g < 3; g++)
        #pragma unroll
        for (int r = 0; r < 16; r++) acc[g][r] = 0.f;

    stage(0, 0); stage(1, 1);
    int cur = 0;
    #pragma unroll 1
    for (int kt = 0; kt < 8; kt++) {
        if (kt < 7) asm volatile("s_waitcnt vmcnt(8)" ::: "memory");
        else        asm volatile("s_waitcnt vmcnt(0)" ::: "memory");
        __builtin_amdgcn_s_barrier();
        __builtin_amdgcn_sched_barrier(0);
        __builtin_amdgcn_s_setprio(1);
        #pragma unroll
        for (int kk = 0; kk < 4; kk++) {
            int kc = kk * 2 + half;
            f16x8 af = *(const f16x8*)&Alds[cur][(kc * 64 + wr * 32 + col) * 8];
            #pragma unroll
            for (int g = 0; g < 3; g++) {
                f16x8 bf = *(const f16x8*)&Blds[cur][(kc * 192 + g * 64 + wc * 32 + col) * 8];
                acc[g] = __builtin_amdgcn_mfma_f32_32x32x16_f16(af, bf, acc[g], 0, 0, 0);
            }
        }
        __builtin_amdgcn_s_setprio(0);
        __builtin_amdgcn_sched_barrier(0);
        __builtin_amdgcn_s_barrier();
        if (kt < 6) stage(cur, kt + 2);
        cur ^= 1;
    }

    // epilogue: gates + h update + decoder partial
    #pragma unroll
    for (int r = 0; r < 16; r++) {
        int m = m0 + wr * 32 + (r & 3) + 8 * (r >> 2) + 4 * half;
        float prev = prevv[r];
        float gr = acc[0][r] + bhr + fmaf(prev, wir, bir);
        float gz = acc[1][r] + bhz + fmaf(prev, wiz, biz);
        float gn = fmaf(prev, win, bin_);
        float rr = sigmoid_fast(gr), zz = sigmoid_fast(gz);
        float nn = tanh_fast(fmaf(rr, acc[2][r] + bhn, gn));
        float hn = fmaf(zz, hpv[r] - nn, nn);            // (1-z)n + z*hp
        hout[(size_t)(e >> 3) * 32768 + m * 8 + (e & 7)] = (f16)hn;
        float v = hn * dw;
        v += __shfl_xor(v, 1);  v += __shfl_xor(v, 2);
        v += __shfl_xor(v, 4);  v += __shfl_xor(v, 8);
        v += __shfl_xor(v, 16);
        if (col == 0) atomicAdd(&out[(size_t)m * TSTEP + t], v);
    }
}

extern "C" void kernel_launch(void* const* d_in, const int* in_sizes, int n_in,
                              void* d_out, int out_size, void* d_ws, size_t ws_size,
                              hipStream_t stream)
{
    const float* x      = (const float*)d_in[0];
    const float* conv_w = (const float*)d_in[1];
    const float* conv_b = (const float*)d_in[2];
    const float* fc_w   = (const float*)d_in[3];
    const float* fc_b   = (const float*)d_in[4];
    const float* w_ih   = (const float*)d_in[5];
    const float* b_ih   = (const float*)d_in[6];
    const float* w_hh   = (const float*)d_in[7];
    const float* b_hh   = (const float*)d_in[8];
    const float* dec_w  = (const float*)d_in[9];
    const float* dec_b  = (const float*)d_in[10];
    float* out = (float*)d_out;

    char* ws = (char*)d_ws;
    // layout (bytes):
    //   [0,         9437184)   convbuf16 [4096][1152] f16
    //   [9437184,  13631488)   h16_a  (k-major [64][4096][8])
    //   [13631488, 17825792)   h16_b  (k-major)
    //   [17825792, 19398656)   w16T   [64][1536][8] f16
    //   [19398656, 19435520)   w16c   [9][32][64] swizzled
    //   [19435520, 20615168)   fcp16  [512][1152] permuted
    f16*  convbuf16 = (f16*)ws;
    f16*  h16_a     = (f16*)(ws + 9437184);
    f16*  h16_b     = (f16*)(ws + 13631488);
    f16*  w16T      = (f16*)(ws + 17825792);
    f16*  w16c      = (f16*)(ws + 19398656);
    f16*  fcp16     = (f16*)(ws + 19435520);

    int prep_n = G3 * EMB + 9 * 32 * 64 + EMB * KFC + B_ * TSTEP;
    prep_kernel<<<(prep_n + 255) / 256, 256, 0, stream>>>(
        w_hh, w16T, conv_w, w16c, fc_w, fcp16, dec_b, out);

    conv_mfma<<<B_ / 8, 256, 0, stream>>>(x, w16c, conv_b, convbuf16);
    fc_mfma<<<dim3(EMB / 64, B_ / 64), 256, 0, stream>>>(convbuf16, fcp16, fc_b, h16_a);

    for (int t = 0; t < TSTEP; t++) {
        const f16* hi = (t & 1) ? h16_b : h16_a;
        f16*       ho = (t & 1) ? h16_a : h16_b;
        gru_step<<<512, 256, 0, stream>>>(
            hi, ho, w16T, b_hh, w_ih, b_ih, dec_w, out, t);
    }
}